// Round 11
// baseline (98.779 us; speedup 1.0000x reference)
//
#include <hip/hip_runtime.h>

// TripletLoss, N=384, D=512, fp32 in, int labels, fp32 scalar out.
// loss = sum_a sum_p sum_n relu(d(a,p)-d(a,n)+1) / num_valid (diag counts as pos)
//
// R17 post-mortem: spin-flag fusion regressed (kernel ~41us): global barrier
// = max over 96 blocks' phase-1 + atomic-RMW polling storm + remote-L2 D
// reads. Dispatch model from R9/R10/R16: dur = 40 (fill) + kernels + ~9/disp
// -> R16's two kernels were only ~13us; ~18us was dispatch overhead.
//
// R18: single dispatch with ZERO cross-block communication. Block b (of 96)
// owns anchors 4b..4b+3 end-to-end: stage the 4 anchor rows as bf16 (+12
// zero rows to fill the 16-row MFMA A operand; garbage C rows discarded),
// stream all 384 B rows through LDS in 4 chunks of 96 rows (96KB), per chunk
// {B-norms from staged bf16, 16 mfma_f32_16x16x32_bf16 per wave, epilogue
// d = sqrt(nA+nB-2G) into a 6KB LDS row buffer}. Phase 2 = the proven
// 384-thread ballot compaction + g-loop + label-only num_valid + atomicAdd
// finisher, reading rows from LDS. Staging converts via v_cvt_pk_bf16_f32
// (1 inst per f32 pair, RNE) instead of the 8-op bit-twiddle. No workspace,
// no flags, no D matrix. R16's proven swizzle/fragment/epilogue layouts.

#define NPTS 384
#define DIM  512
#define NT   384
#define NW   (NT / 64)     // 6 waves
#define APB  4             // anchors per block
#define NB   (NPTS / APB)  // 96 blocks
#define CHROWS 96          // B rows per chunk
#define NCH  (NPTS / CHROWS)

typedef __attribute__((ext_vector_type(8))) short bf16x8;
typedef __attribute__((ext_vector_type(4))) float f32x4;

__device__ __forceinline__ uint cvt_pk_bf16(float lo, float hi) {
    uint r;                       // D[15:0]=bf16(lo), D[31:16]=bf16(hi), RNE
    asm("v_cvt_pk_bf16_f32 %0, %1, %2" : "=v"(r) : "v"(lo), "v"(hi));
    return r;
}

__global__ __launch_bounds__(NT) void triplet_one(
    const float* __restrict__ X,
    const int*   __restrict__ labels,
    float*       __restrict__ out)
{
    __shared__ ushort s_A[16 * 512]     __attribute__((aligned(16)));  // 16 KB
    __shared__ ushort s_B[CHROWS * 512] __attribute__((aligned(16)));  // 96 KB
    __shared__ float  s_nA[16];
    __shared__ float  s_nB[CHROWS];
    __shared__ float  s_drow[APB][NPTS];                               // 6 KB
    __shared__ float  s_dp[NPTS];
    __shared__ float  s_dn[NPTS];
    __shared__ int    s_lab[NPTS] __attribute__((aligned(16)));
    __shared__ int    s_cp[NW], s_cn[NW];
    __shared__ float  s_red[NW];
    __shared__ int    s_nv[NW];

    const int t    = threadIdx.x;
    const int lane = t & 63, w = t >> 6;
    const int b    = blockIdx.x;
    const int a0   = b * APB;

    const float4* X4 = (const float4*)X;          // row pitch DIM/4 = 128

    // ---- stage A: 4 real rows -> s_A rows 0..3 (swizzled bf16) -------------
    if (t < 512) {
        const int row = t >> 7, col4 = t & 127;   // row 0..3
        const float4 v = X4[(size_t)(a0 + row) * 128 + col4];
        const uint lo = cvt_pk_bf16(v.x, v.y);
        const uint hi = cvt_pk_bf16(v.z, v.w);
        const int off = (col4 * 8) ^ (row << 4);  // row<4 -> row&7 == row
        *(uint2*)((char*)s_A + row * 1024 + off) = make_uint2(lo, hi);
    }
    {   // zero rows 4..15 (their C rows are discarded; keep values benign)
        uint2* z = (uint2*)((char*)s_A + 4 * 1024);
#pragma unroll
        for (int i = 0; i < 4; ++i) z[i * NT + t] = make_uint2(0u, 0u);
    }
    s_lab[t] = labels[t];

    // ---- B chunk staging: 96 rows x 1KB, swizzled bf16, coalesced ----------
#define STAGE_B(c_) { \
    _Pragma("unroll 8") \
    for (int p = 0; p < 32; ++p) { \
        const int idx = p * NT + t;               /* 0..12287 */ \
        const int row = idx >> 7, col4 = idx & 127; \
        const float4 v = X4[(size_t)((c_) * CHROWS + row) * 128 + col4]; \
        const uint lo = cvt_pk_bf16(v.x, v.y); \
        const uint hi = cvt_pk_bf16(v.z, v.w); \
        const int off = (col4 * 8) ^ ((row & 7) << 4); \
        *(uint2*)((char*)s_B + row * 1024 + off) = make_uint2(lo, hi); \
    } }

    STAGE_B(0);
    __syncthreads();

    // ---- per-chunk: norms + MFMA + epilogue, stage next chunk --------------
    const int ar = lane & 15;                     // A local row for this lane
    const int kg = (lane >> 4) * 16;              // k-group byte offset
    const char* pa = (const char*)s_A + ar * 1024;

    for (int c = 0; c < NCH; ++c) {
        // B-norms from staged bf16: thread -> row t>>2, k-quarter t&3
        {
            const int row = t >> 2, q = t & 3;
            const char* src = (const char*)s_B + row * 1024;
            float nrm = 0.f;
#pragma unroll
            for (int i = 0; i < 16; ++i) {
                const int cb = q * 256 + i * 16;
                const bf16x8 hv = *(const bf16x8*)(src + (cb ^ ((row & 7) << 4)));
#pragma unroll
                for (int j = 0; j < 8; ++j) {
                    const float f = __uint_as_float(((uint)(ushort)hv[j]) << 16);
                    nrm = fmaf(f, f, nrm);
                }
            }
            nrm += __shfl_xor(nrm, 1, 64);
            nrm += __shfl_xor(nrm, 2, 64);
            if ((t & 3) == 0) s_nB[row] = nrm;
        }
        if (c == 0 && t < 16) {                   // A-norms once (rows 0..3)
            const int row = t >> 2, q = t & 3;
            const char* src = (const char*)s_A + row * 1024;
            float nrm = 0.f;
#pragma unroll
            for (int i = 0; i < 16; ++i) {
                const int cb = q * 256 + i * 16;
                const bf16x8 hv = *(const bf16x8*)(src + (cb ^ (row << 4)));
#pragma unroll
                for (int j = 0; j < 8; ++j) {
                    const float f = __uint_as_float(((uint)(ushort)hv[j]) << 16);
                    nrm = fmaf(f, f, nrm);
                }
            }
            nrm += __shfl_xor(nrm, 1, 64);
            nrm += __shfl_xor(nrm, 2, 64);
            if ((t & 3) == 0) s_nA[row] = nrm;
        }

        // Gram: wave w covers chunk cols [w*16, w*16+16)
        f32x4 acc = {0.f, 0.f, 0.f, 0.f};
        const int br = w * 16 + (lane & 15);      // chunk-local B row = C col
        const char* pb = (const char*)s_B + br * 1024;
#pragma unroll
        for (int kt = 0; kt < 16; ++kt) {
            const int kb = kt * 64 + kg;
            const bf16x8 af = *(const bf16x8*)(pa + (kb ^ ((ar & 7) << 4)));
            const bf16x8 bv = *(const bf16x8*)(pb + (kb ^ ((br & 7) << 4)));
            acc = __builtin_amdgcn_mfma_f32_16x16x32_bf16(af, bv, acc, 0, 0, 0);
        }
        __syncthreads();                          // norms visible; s_B reads done

        // epilogue: d = sqrt(max(nA+nB-2G,0)); diag forced 0; keep rows < 4
        {
            const int jl = w * 16 + (lane & 15);  // == br
            const int j  = c * CHROWS + jl;       // global column
            const float nB = s_nB[jl];
#pragma unroll
            for (int v = 0; v < 4; ++v) {
                const int r = (lane >> 4) * 4 + v;
                if (r < 4) {
                    const float d2 = s_nA[r] + nB - 2.f * acc[v];
                    s_drow[r][j] = (a0 + r == j) ? 0.f : sqrtf(fmaxf(d2, 0.f));
                }
            }
        }
        if (c < NCH - 1) STAGE_B(c + 1);          // overwrite s_B (reads done)
        __syncthreads();
    }

    // ---- phase 2: proven compaction + pair sum per anchor (R17 g-loop) -----
    const unsigned long long blw = (1ull << lane) - 1ull;   // lane<64, safe
    float local = 0.f;
#pragma unroll 1
    for (int g = 0; g < APB; ++g) {
        const int lab_a = s_lab[a0 + g];
        const float dv  = s_drow[g][t];
        const bool  isp = (s_lab[t] == lab_a);    // diag j==a counts as pos
        const unsigned long long m = __ballot(isp);
        __syncthreads();                          // prev-g s_dp/s_dn reads done
        if (lane == 0) { s_cp[w] = __popcll(m); s_cn[w] = 64 - __popcll(m); }
        __syncthreads();

        int basep = 0, basen = 0, np = 0, nn = 0;
#pragma unroll
        for (int i = 0; i < NW; ++i) {
            if (i < w) { basep += s_cp[i]; basen += s_cn[i]; }
            np += s_cp[i]; nn += s_cn[i];
        }
        if (isp) s_dp[basep + __popcll(m  & blw)] = dv;
        else     s_dn[basen + __popcll(~m & blw)] = dv;
        __syncthreads();

        const bool  va  = (t < nn);
        const float dna = va ? s_dn[t] : 0.f;
        for (int p = 0; p < np; ++p) {
            const float cpm = s_dp[p] + 1.0f;     // MARGIN
            if (va) local += fmaxf(cpm - dna, 0.f);
        }
    }

    // ---- global num_valid from labels alone (identical in every block) -----
    const int myl = s_lab[t];
    int npt = 0;
    const int4* L4 = (const int4*)s_lab;
#pragma unroll 8
    for (int j4 = 0; j4 < NPTS / 4; ++j4) {
        const int4 l = L4[j4];                    // broadcast read
        npt += (l.x == myl) + (l.y == myl) + (l.z == myl) + (l.w == myl);
    }
    int nvl = npt * (NPTS - npt);

    // ---- block reduce + atomic finish --------------------------------------
    for (int off = 32; off; off >>= 1) {
        local += __shfl_down(local, off, 64);
        nvl   += __shfl_down(nvl,   off, 64);
    }
    if (lane == 0) { s_red[w] = local; s_nv[w] = nvl; }
    __syncthreads();
    if (t == 0) {
        float bs = 0.f; int nv = 0;
#pragma unroll
        for (int i = 0; i < NW; ++i) { bs += s_red[i]; nv += s_nv[i]; }
        // out is memset to 0 by the harness before each verified launch
        atomicAdd(out, (float)((double)bs / ((double)nv + 1e-16)));
    }
#undef STAGE_B
}

extern "C" void kernel_launch(void* const* d_in, const int* in_sizes, int n_in,
                              void* d_out, int out_size, void* d_ws, size_t ws_size,
                              hipStream_t stream) {
    (void)in_sizes; (void)n_in; (void)out_size; (void)d_ws; (void)ws_size;
    const float* X      = (const float*)d_in[0];
    const int*   labels = (const int*)d_in[1];
    triplet_one<<<dim3(NB), dim3(NT), 0, stream>>>(X, labels, (float*)d_out);
}

// Round 12
// 89.759 us; speedup vs baseline: 1.1005x; 1.1005x over previous
//
#include <hip/hip_runtime.h>

// TripletLoss, N=384, D=512, fp32 in, int labels, fp32 scalar out.
// loss = sum_a sum_p sum_n relu(d(a,p)-d(a,n)+1) / num_valid (diag counts as pos)
//
// R18 post-mortem: full per-block ownership re-hit the per-CU line wall
// (772KB X re-read/block -> 49-52us kernel). R16 two-dispatch (70.8) is best.
// R17 proved the fused structure CORRECT (absmax 0.0) but its barrier cost
// ~41us: (a) 96x96 continuous atomic-RMW polling storm, (b) global wait on
// all 96 blocks. Its anchor assignment a=4b..4b+3 is already panel-local
// (blocks i*8..i*8+7 compute AND consume rows 32i..32i+31).
//
// R19 = R17 verbatim except the barrier:
//   - wait only on the 8 flags of the block's own row panel (partial order,
//     overlaps phase 2 with other panels' phase-1 tails);
//   - poll with __hip_atomic_load (coherent load, NO RMW) + s_sleep backoff;
//   - bounded spin -> escape gives absmax fail, never a hang.
// Everything else (MFMA tile engine, swizzle, norms, epilogue, compaction,
// num_valid, finisher) is the R17-proven code unchanged.

#define NPTS 384
#define DIM  512
#define NT   384
#define NW   (NT / 64)     // 6 waves
#define NBI  12            // 32-row A panels
#define NBJ  8             // 48-col B panels
#define NB   (NBI * NBJ)   // 96 blocks
#define APB  4             // anchors per block in phase 2 (panel-local!)
#define MAGIC 0x7FA1B2C3u  // bytes all distinct -> != any repeated-byte poison
#define FLAG_STRIDE 16     // u32 stride between flag cells (64B apart)

typedef __attribute__((ext_vector_type(8))) short bf16x8;
typedef __attribute__((ext_vector_type(4))) float f32x4;

__device__ __forceinline__ ushort f2bf(float f) {     // RNE f32 -> bf16
    uint u = __float_as_uint(f);
    u += 0x7fffu + ((u >> 16) & 1u);
    return (ushort)(u >> 16);
}

__global__ __launch_bounds__(NT) void triplet_one(
    const float* __restrict__ X,
    const int*   __restrict__ labels,
    float*       __restrict__ D,       // ws: 384*384*4 B
    unsigned*    __restrict__ flags,   // ws + 589824: 96 cells, stride 16 u32
    float*       __restrict__ out)
{
    __shared__ ushort s_T[80 * 512] __attribute__((aligned(16)));  // 80 KB
    __shared__ float  s_nrmp[4][80];
    __shared__ float  s_dp[NPTS];
    __shared__ float  s_dn[NPTS];
    __shared__ int    s_lab[NPTS] __attribute__((aligned(16)));
    __shared__ int    s_cp[NW], s_cn[NW];
    __shared__ float  s_red[NW];
    __shared__ int    s_nv[NW];

    const int t    = threadIdx.x;
    const int lane = t & 63, w = t >> 6;
    const int b    = blockIdx.x;
    const int bi   = (b >> 3) * 32;        // A panel: 32 rows
    const int bj   = (b & 7)  * 48;        // B panel: 48 rows (C cols)

    const float4* X4 = (const float4*)X;   // row pitch DIM/4 = 128

    // ---- phase 1a: stage 80 rows (32 A + 48 B) as swizzled bf16 ------------
#pragma unroll
    for (int p = 0; p < 27; ++p) {
        const int idx = p * NT + t;        // 0..10239 used
        if (idx < 80 * 128) {
            const int row  = idx >> 7;     // LDS row 0..79
            const int col4 = idx & 127;
            const int grow = (row < 32) ? (bi + row) : (bj + row - 32);
            const float4 v = X4[(size_t)grow * 128 + col4];
            const uint lo = (uint)f2bf(v.x) | ((uint)f2bf(v.y) << 16);
            const uint hi = (uint)f2bf(v.z) | ((uint)f2bf(v.w) << 16);
            const int off = (col4 * 8) ^ ((row & 7) << 4);   // 16B-grain XOR
            *(uint2*)((char*)s_T + row * 1024 + off) = make_uint2(lo, hi);
        }
    }
    s_lab[t] = labels[t];
    __syncthreads();

    // ---- phase 1b: norms from staged bf16 (waves 0..4, 16 rows each) -------
    if (w < 5) {
        const int row = w * 16 + (lane & 15);    // 0..79
        const int q   = lane >> 4;               // k-quarter
        const char* src = (const char*)s_T + row * 1024;
        float nrm = 0.f;
#pragma unroll
        for (int c = 0; c < 16; ++c) {
            const int cb = q * 256 + c * 16;
            const bf16x8 hv = *(const bf16x8*)(src + (cb ^ ((row & 7) << 4)));
#pragma unroll
            for (int j = 0; j < 8; ++j) {
                const float f = __uint_as_float(((uint)(ushort)hv[j]) << 16);
                nrm = fmaf(f, f, nrm);
            }
        }
        s_nrmp[q][row] = nrm;
    }

    // ---- phase 1c: Gram via mfma_f32_16x16x32_bf16 (2x3 wave grid) ---------
    f32x4 acc = {0.f, 0.f, 0.f, 0.f};
    const int wr  = w / 3, wc = w % 3;
    const int ar  = wr * 16 + (lane & 15);       // A local row
    const int brl = 32 + wc * 16 + (lane & 15);  // B local row in s_T
    const char* pa = (const char*)s_T + ar  * 1024;
    const char* pb = (const char*)s_T + brl * 1024;
    const int kg = (lane >> 4) * 16;
#pragma unroll
    for (int kt = 0; kt < 16; ++kt) {
        const int kb = kt * 64 + kg;
        const bf16x8 af = *(const bf16x8*)(pa + (kb ^ ((ar  & 7) << 4)));
        const bf16x8 bv = *(const bf16x8*)(pb + (kb ^ ((brl & 7) << 4)));
        acc = __builtin_amdgcn_mfma_f32_16x16x32_bf16(af, bv, acc, 0, 0, 0);
    }
    __syncthreads();                             // s_nrmp complete

    // ---- phase 1d: d = sqrt(max(nA+nB-2G, 0)); diag forced 0 ---------------
    {
        const int bcol = wc * 16 + (lane & 15);
        const float nB = s_nrmp[0][32 + bcol] + s_nrmp[1][32 + bcol] +
                         s_nrmp[2][32 + bcol] + s_nrmp[3][32 + bcol];
#pragma unroll
        for (int v = 0; v < 4; ++v) {
            const int il = wr * 16 + (lane >> 4) * 4 + v;
            const float nA = s_nrmp[0][il] + s_nrmp[1][il] +
                             s_nrmp[2][il] + s_nrmp[3][il];
            const float d2 = nA + nB - 2.f * acc[v];
            const int gi = bi + il, gj = bj + bcol;
            D[(size_t)gi * NPTS + gj] = (gi == gj) ? 0.f
                                                   : sqrtf(fmaxf(d2, 0.f));
        }
    }

    // ---- per-PANEL wait: flag own tile, poll only this panel's 8 flags -----
    __threadfence();                             // flush this block's D writes
    __syncthreads();                             // whole block's writes issued
    if (t == 0) atomicExch(&flags[b * FLAG_STRIDE], MAGIC);
    if (t < NBJ) {                               // 8 lanes poll 8 distinct cells
        const unsigned* cell = &flags[((b >> 3) * NBJ + t) * FLAG_STRIDE];
        int spins = 0;
        while (__hip_atomic_load(cell, __ATOMIC_RELAXED,
                                 __HIP_MEMORY_SCOPE_AGENT) != MAGIC &&
               ++spins < (1 << 18)) {
            __builtin_amdgcn_s_sleep(1);         // back off, no RMW traffic
        }
    }
    __syncthreads();
    __threadfence();                             // acquire before reading D

    // ---- phase 2: 4 panel-local anchors, proven compaction + pair sum ------
    const unsigned long long blw = (1ull << lane) - 1ull;   // lane<64, safe
    float local = 0.f;
#pragma unroll 1
    for (int g = 0; g < APB; ++g) {
        const int a     = b * APB + g;           // in panel b>>3 by construction
        const int lab_a = s_lab[a];
        const float dv  = D[(size_t)a * NPTS + t];
        const bool  isp = (s_lab[t] == lab_a);   // diag j==a counts as pos
        const unsigned long long m = __ballot(isp);
        __syncthreads();                         // prev-g s_dp/s_dn reads done
        if (lane == 0) { s_cp[w] = __popcll(m); s_cn[w] = 64 - __popcll(m); }
        __syncthreads();

        int basep = 0, basen = 0, np = 0, nn = 0;
#pragma unroll
        for (int i = 0; i < NW; ++i) {
            if (i < w) { basep += s_cp[i]; basen += s_cn[i]; }
            np += s_cp[i]; nn += s_cn[i];
        }
        if (isp) s_dp[basep + __popcll(m  & blw)] = dv;
        else     s_dn[basen + __popcll(~m & blw)] = dv;
        __syncthreads();

        const bool  va  = (t < nn);
        const float dna = va ? s_dn[t] : 0.f;
        for (int p = 0; p < np; ++p) {
            const float c = s_dp[p] + 1.0f;      // MARGIN
            if (va) local += fmaxf(c - dna, 0.f);
        }
    }

    // ---- global num_valid from labels alone (identical in every block) -----
    const int myl = s_lab[t];
    int npt = 0;
    const int4* L4 = (const int4*)s_lab;
#pragma unroll 8
    for (int j4 = 0; j4 < NPTS / 4; ++j4) {
        const int4 l = L4[j4];                   // broadcast read
        npt += (l.x == myl) + (l.y == myl) + (l.z == myl) + (l.w == myl);
    }
    int nvl = npt * (NPTS - npt);

    // ---- block reduce + atomic finish --------------------------------------
    for (int off = 32; off; off >>= 1) {
        local += __shfl_down(local, off, 64);
        nvl   += __shfl_down(nvl,   off, 64);
    }
    if (lane == 0) { s_red[w] = local; s_nv[w] = nvl; }
    __syncthreads();
    if (t == 0) {
        float bs = 0.f; int nv = 0;
#pragma unroll
        for (int i = 0; i < NW; ++i) { bs += s_red[i]; nv += s_nv[i]; }
        // out is memset to 0 by the harness before each verified launch
        atomicAdd(out, (float)((double)bs / ((double)nv + 1e-16)));
    }
}

extern "C" void kernel_launch(void* const* d_in, const int* in_sizes, int n_in,
                              void* d_out, int out_size, void* d_ws, size_t ws_size,
                              hipStream_t stream) {
    (void)in_sizes; (void)n_in; (void)out_size; (void)ws_size;
    const float* X      = (const float*)d_in[0];
    const int*   labels = (const int*)d_in[1];

    float*    Dmat  = (float*)d_ws;                          // 589824 B
    unsigned* flags = (unsigned*)((char*)d_ws + 589824);     // 96 x 64 B

    triplet_one<<<dim3(NB), dim3(NT), 0, stream>>>(X, labels, Dmat, flags,
                                                   (float*)d_out);
}

// Round 13
// 69.764 us; speedup vs baseline: 1.4159x; 1.2866x over previous
//
#include <hip/hip_runtime.h>

// TripletLoss, N=384, D=512, fp32 in, int labels, fp32 scalar out.
// loss = sum_a sum_p sum_n relu(d(a,p)-d(a,n)+1) / num_valid (diag counts as pos)
//
// R19 post-mortem: panel-local wait + load-only polling == R17 (kernel ~40us)
// -> sync mechanism was never the cost; the fused phase-1's 27-deep staging
// chain under the fill's L3-drain window is (R11 counters: VALUBusy 7%,
// MfmaUtil 0.4% on the same structure). Two-dispatch R16 (70.8us) remains
// best: dur = 40 (fixed 268MB ws re-poison) + kernels + ~5/dispatch.
//
// R20 = R16 with two latency-targeted micro-opts, no structural change:
//  K1: two-phase staging - issue 16 global float4 loads into registers
//      (static unroll -> 16 misses in flight vs compiler's ~8), THEN convert
//      (proven f2bf RNE bit-twiddle, absmax 0.0) + swizzled LDS store. x2.
//  K2: 96 blocks x 4 anchors using the R17/R19-proven g-loop compaction
//      (smaller ramp than 384 blocks; D rows panel-contiguous), label-only
//      num_valid + atomicAdd finisher (all absmax-0.0-verified pieces).

#define NPTS 384
#define DIM  512
#define NT2  384
#define NW2  (NT2 / 64)  // 6 waves
#define APB  4           // anchors per K2 block
#define NB2  (NPTS / APB)

typedef __attribute__((ext_vector_type(8))) short bf16x8;
typedef __attribute__((ext_vector_type(4))) float f32x4;

__device__ __forceinline__ ushort f2bf(float f) {     // RNE f32 -> bf16
    uint u = __float_as_uint(f);
    u += 0x7fffu + ((u >> 16) & 1u);
    return (ushort)(u >> 16);
}

// ---------------- K1: distance tiles via bf16 MFMA Gram ---------------------
__global__ __launch_bounds__(256) void dist_mfma(const float* __restrict__ X,
                                                 float* __restrict__ D) {
    __shared__ ushort s_A[32 * 512] __attribute__((aligned(16)));  // 32 KB
    __shared__ ushort s_B[32 * 512] __attribute__((aligned(16)));  // 32 KB
    __shared__ float  s_nrmp[4][64];                               // 1 KB

    const int t    = threadIdx.x;
    const int lane = t & 63, w = t >> 6;
    const int wr   = w >> 1,  wc = w & 1;        // 2x2 wave grid of 16x16 C-tiles
    const int bi   = blockIdx.y * 32;
    const int bj   = blockIdx.x * 32;

    const float4* X4 = (const float4*)X;         // row pitch DIM/4 = 128

    // ---- stage A/B as bf16, swizzled; two-phase 16-deep load batches -------
#pragma unroll
    for (int h = 0; h < 2; ++h) {
        float4 vbuf[16];                         // static -> registers, 16 misses in flight
#pragma unroll
        for (int p = 0; p < 16; ++p) {
            const int idx  = (h * 16 + p) * 256 + t;     // 0..8191
            const int side = idx >> 12;                  // 0=A, 1=B
            const int row  = (idx >> 7) & 31;
            const int col4 = idx & 127;
            const int grow = (side ? bj : bi) + row;
            vbuf[p] = X4[(size_t)grow * 128 + col4];
        }
#pragma unroll
        for (int p = 0; p < 16; ++p) {
            const int idx  = (h * 16 + p) * 256 + t;
            const int side = idx >> 12;
            const int row  = (idx >> 7) & 31;
            const int col4 = idx & 127;
            const float4 v = vbuf[p];
            const uint lo = (uint)f2bf(v.x) | ((uint)f2bf(v.y) << 16);
            const uint hi = (uint)f2bf(v.z) | ((uint)f2bf(v.w) << 16);
            const int off = (col4 * 8) ^ ((row & 7) << 4);   // 16B-grain XOR
            char* dst = (side ? (char*)s_B : (char*)s_A) + row * 1024 + off;
            *(uint2*)dst = make_uint2(lo, hi);
        }
    }
    __syncthreads();

    // ---- norms from the staged bf16 values: lane=row, wave=k-quarter -------
    {
        const int row  = lane;                   // 0..31 A rows, 32..63 B rows
        const int side = row >> 5, r = row & 31;
        const char* src = (side ? (const char*)s_B : (const char*)s_A) + r * 1024;
        float nrm = 0.f;
#pragma unroll
        for (int c = 0; c < 16; ++c) {
            const int cb = (w * 16 + c) * 16;    // 16B chunk within the 1KB row
            const bf16x8 hv = *(const bf16x8*)(src + (cb ^ ((r & 7) << 4)));
#pragma unroll
            for (int j = 0; j < 8; ++j) {
                const float f = __uint_as_float(((uint)(ushort)hv[j]) << 16);
                nrm = fmaf(f, f, nrm);
            }
        }
        s_nrmp[w][row] = nrm;
    }

    // ---- Gram tile: 16 k-chunks x mfma_f32_16x16x32_bf16 -------------------
    f32x4 acc = {0.f, 0.f, 0.f, 0.f};
    const int ar = wr * 16 + (lane & 15);        // A local row fed by this lane
    const int br = wc * 16 + (lane & 15);        // B local row (= C col)
    const char* pa = (const char*)s_A + ar * 1024;
    const char* pb = (const char*)s_B + br * 1024;
    const int kg = (lane >> 4) * 16;             // lane's k-group byte offset
#pragma unroll
    for (int kt = 0; kt < 16; ++kt) {
        const int kb = kt * 64 + kg;
        const bf16x8 af = *(const bf16x8*)(pa + (kb ^ ((ar & 7) << 4)));
        const bf16x8 bf = *(const bf16x8*)(pb + (kb ^ ((br & 7) << 4)));
        acc = __builtin_amdgcn_mfma_f32_16x16x32_bf16(af, bf, acc, 0, 0, 0);
    }
    __syncthreads();                              // s_nrmp complete

    // ---- epilogue: d = sqrt(max(nA + nB - 2*G, 0)); diag forced 0 ----------
    const float nB = s_nrmp[0][32 + br] + s_nrmp[1][32 + br] +
                     s_nrmp[2][32 + br] + s_nrmp[3][32 + br];
#pragma unroll
    for (int v = 0; v < 4; ++v) {
        const int il = wr * 16 + (lane >> 4) * 4 + v;    // C row -> A local row
        const float nA = s_nrmp[0][il] + s_nrmp[1][il] +
                         s_nrmp[2][il] + s_nrmp[3][il];
        const float d2 = nA + nB - 2.f * acc[v];
        const int gi = bi + il, gj = bj + br;
        D[(size_t)gi * NPTS + gj] = (gi == gj) ? 0.f : sqrtf(fmaxf(d2, 0.f));
    }
}

// ------- K2: 96 blocks x 4 anchors, proven g-loop compaction + finish -------
__global__ __launch_bounds__(NT2) void pair_reduce(const float* __restrict__ D,
                                                   const int* __restrict__ labels,
                                                   float* __restrict__ out) {
    __shared__ float s_dp[NPTS];
    __shared__ float s_dn[NPTS];
    __shared__ int   s_lab[NPTS] __attribute__((aligned(16)));
    __shared__ int   s_cp[NW2], s_cn[NW2];
    __shared__ float s_red[NW2];
    __shared__ int   s_nv[NW2];

    const int t = threadIdx.x, lane = t & 63, w = t >> 6;
    const int b = blockIdx.x;

    s_lab[t] = labels[t];
    __syncthreads();

    const unsigned long long blw = (1ull << lane) - 1ull;   // lane<64, safe
    float local = 0.f;
#pragma unroll 1
    for (int g = 0; g < APB; ++g) {
        const int a     = b * APB + g;
        const int lab_a = s_lab[a];
        const float dv  = D[(size_t)a * NPTS + t];
        const bool  isp = (s_lab[t] == lab_a);   // diag j==a counts as pos
        const unsigned long long m = __ballot(isp);
        __syncthreads();                         // prev-g s_dp/s_dn reads done
        if (lane == 0) { s_cp[w] = __popcll(m); s_cn[w] = 64 - __popcll(m); }
        __syncthreads();

        int basep = 0, basen = 0, np = 0, nn = 0;
#pragma unroll
        for (int i = 0; i < NW2; ++i) {
            if (i < w) { basep += s_cp[i]; basen += s_cn[i]; }
            np += s_cp[i]; nn += s_cn[i];
        }
        if (isp) s_dp[basep + __popcll(m  & blw)] = dv;
        else     s_dn[basen + __popcll(~m & blw)] = dv;
        __syncthreads();

        const bool  va  = (t < nn);
        const float dna = va ? s_dn[t] : 0.f;
        for (int p = 0; p < np; ++p) {
            const float c = s_dp[p] + 1.0f;      // MARGIN
            if (va) local += fmaxf(c - dna, 0.f);
        }
    }

    // ---- global num_valid from labels alone (identical in every block) -----
    const int myl = s_lab[t];
    int npt = 0;
    const int4* L4 = (const int4*)s_lab;
#pragma unroll 8
    for (int j4 = 0; j4 < NPTS / 4; ++j4) {
        const int4 l = L4[j4];                   // broadcast read
        npt += (l.x == myl) + (l.y == myl) + (l.z == myl) + (l.w == myl);
    }
    int nvl = npt * (NPTS - npt);

    // ---- block reduce + atomic finish --------------------------------------
    for (int off = 32; off; off >>= 1) {
        local += __shfl_down(local, off, 64);
        nvl   += __shfl_down(nvl,   off, 64);
    }
    if (lane == 0) { s_red[w] = local; s_nv[w] = nvl; }
    __syncthreads();
    if (t == 0) {
        float bs = 0.f; int nv = 0;
#pragma unroll
        for (int i = 0; i < NW2; ++i) { bs += s_red[i]; nv += s_nv[i]; }
        // out is memset to 0 by the harness before each verified launch
        atomicAdd(out, (float)((double)bs / ((double)nv + 1e-16)));
    }
}

extern "C" void kernel_launch(void* const* d_in, const int* in_sizes, int n_in,
                              void* d_out, int out_size, void* d_ws, size_t ws_size,
                              hipStream_t stream) {
    (void)in_sizes; (void)n_in; (void)out_size; (void)ws_size;
    const float* X      = (const float*)d_in[0];
    const int*   labels = (const int*)d_in[1];

    float* Dmat = (float*)d_ws;                  // 589824 B, rewritten each run

    dist_mfma  <<<dim3(NPTS / 32, NPTS / 32), dim3(256), 0, stream>>>(X, Dmat);
    pair_reduce<<<dim3(NB2),                  dim3(NT2), 0, stream>>>(Dmat, labels,
                                                                     (float*)d_out);
}

// Round 14
// 69.529 us; speedup vs baseline: 1.4207x; 1.0034x over previous
//
#include <hip/hip_runtime.h>

// TripletLoss, N=384, D=512, fp32 in, int labels, fp32 scalar out.
// loss = sum_a sum_p sum_n relu(d(a,p)-d(a,n)+1) / num_valid (diag counts as pos)
//
// R20 post-mortem: 69.8us = 40 (fixed ws-poison fill) + ~10/dispatch x2 +
// ~10us kernels. Two-dispatch floor ~= 68. Fused single-dispatch measured
// 40-52us kernel across 3 independent implementations (unexplained) - not
// retried. R21 = R20 with ONE change: K1 staging converts via hardware
// v_cvt_pk_bf16_f32 (R18-proven, 1 inst/pair, RNE, one-ulp absmax 0.0078)
// instead of the 5-op f2bf bit-twiddle -> ~2.5x less staging VALU on K1's
// critical path. Everything else verbatim from R20 (absmax 0.0).

#define NPTS 384
#define DIM  512
#define NT2  384
#define NW2  (NT2 / 64)  // 6 waves
#define APB  4           // anchors per K2 block
#define NB2  (NPTS / APB)

typedef __attribute__((ext_vector_type(8))) short bf16x8;
typedef __attribute__((ext_vector_type(4))) float f32x4;

__device__ __forceinline__ uint cvt_pk_bf16(float lo, float hi) {
    uint r;                       // D[15:0]=bf16(lo), D[31:16]=bf16(hi), RNE
    asm("v_cvt_pk_bf16_f32 %0, %1, %2" : "=v"(r) : "v"(lo), "v"(hi));
    return r;
}

// ---------------- K1: distance tiles via bf16 MFMA Gram ---------------------
__global__ __launch_bounds__(256) void dist_mfma(const float* __restrict__ X,
                                                 float* __restrict__ D) {
    __shared__ ushort s_A[32 * 512] __attribute__((aligned(16)));  // 32 KB
    __shared__ ushort s_B[32 * 512] __attribute__((aligned(16)));  // 32 KB
    __shared__ float  s_nrmp[4][64];                               // 1 KB

    const int t    = threadIdx.x;
    const int lane = t & 63, w = t >> 6;
    const int wr   = w >> 1,  wc = w & 1;        // 2x2 wave grid of 16x16 C-tiles
    const int bi   = blockIdx.y * 32;
    const int bj   = blockIdx.x * 32;

    const float4* X4 = (const float4*)X;         // row pitch DIM/4 = 128

    // ---- stage A/B as bf16, swizzled; two-phase 16-deep load batches -------
#pragma unroll
    for (int h = 0; h < 2; ++h) {
        float4 vbuf[16];                         // static -> registers, 16 misses in flight
#pragma unroll
        for (int p = 0; p < 16; ++p) {
            const int idx  = (h * 16 + p) * 256 + t;     // 0..8191
            const int side = idx >> 12;                  // 0=A, 1=B
            const int row  = (idx >> 7) & 31;
            const int col4 = idx & 127;
            const int grow = (side ? bj : bi) + row;
            vbuf[p] = X4[(size_t)grow * 128 + col4];
        }
#pragma unroll
        for (int p = 0; p < 16; ++p) {
            const int idx  = (h * 16 + p) * 256 + t;
            const int side = idx >> 12;
            const int row  = (idx >> 7) & 31;
            const int col4 = idx & 127;
            const float4 v = vbuf[p];
            const uint lo = cvt_pk_bf16(v.x, v.y);       // HW packed convert
            const uint hi = cvt_pk_bf16(v.z, v.w);
            const int off = (col4 * 8) ^ ((row & 7) << 4);   // 16B-grain XOR
            char* dst = (side ? (char*)s_B : (char*)s_A) + row * 1024 + off;
            *(uint2*)dst = make_uint2(lo, hi);
        }
    }
    __syncthreads();

    // ---- norms from the staged bf16 values: lane=row, wave=k-quarter -------
    {
        const int row  = lane;                   // 0..31 A rows, 32..63 B rows
        const int side = row >> 5, r = row & 31;
        const char* src = (side ? (const char*)s_B : (const char*)s_A) + r * 1024;
        float nrm = 0.f;
#pragma unroll
        for (int c = 0; c < 16; ++c) {
            const int cb = (w * 16 + c) * 16;    // 16B chunk within the 1KB row
            const bf16x8 hv = *(const bf16x8*)(src + (cb ^ ((r & 7) << 4)));
#pragma unroll
            for (int j = 0; j < 8; ++j) {
                const float f = __uint_as_float(((uint)(ushort)hv[j]) << 16);
                nrm = fmaf(f, f, nrm);
            }
        }
        s_nrmp[w][row] = nrm;
    }

    // ---- Gram tile: 16 k-chunks x mfma_f32_16x16x32_bf16 -------------------
    f32x4 acc = {0.f, 0.f, 0.f, 0.f};
    const int ar = wr * 16 + (lane & 15);        // A local row fed by this lane
    const int br = wc * 16 + (lane & 15);        // B local row (= C col)
    const char* pa = (const char*)s_A + ar * 1024;
    const char* pb = (const char*)s_B + br * 1024;
    const int kg = (lane >> 4) * 16;             // lane's k-group byte offset
#pragma unroll
    for (int kt = 0; kt < 16; ++kt) {
        const int kb = kt * 64 + kg;
        const bf16x8 af = *(const bf16x8*)(pa + (kb ^ ((ar & 7) << 4)));
        const bf16x8 bf = *(const bf16x8*)(pb + (kb ^ ((br & 7) << 4)));
        acc = __builtin_amdgcn_mfma_f32_16x16x32_bf16(af, bf, acc, 0, 0, 0);
    }
    __syncthreads();                              // s_nrmp complete

    // ---- epilogue: d = sqrt(max(nA + nB - 2*G, 0)); diag forced 0 ----------
    const float nB = s_nrmp[0][32 + br] + s_nrmp[1][32 + br] +
                     s_nrmp[2][32 + br] + s_nrmp[3][32 + br];
#pragma unroll
    for (int v = 0; v < 4; ++v) {
        const int il = wr * 16 + (lane >> 4) * 4 + v;    // C row -> A local row
        const float nA = s_nrmp[0][il] + s_nrmp[1][il] +
                         s_nrmp[2][il] + s_nrmp[3][il];
        const float d2 = nA + nB - 2.f * acc[v];
        const int gi = bi + il, gj = bj + br;
        D[(size_t)gi * NPTS + gj] = (gi == gj) ? 0.f : sqrtf(fmaxf(d2, 0.f));
    }
}

// ------- K2: 96 blocks x 4 anchors, proven g-loop compaction + finish -------
__global__ __launch_bounds__(NT2) void pair_reduce(const float* __restrict__ D,
                                                   const int* __restrict__ labels,
                                                   float* __restrict__ out) {
    __shared__ float s_dp[NPTS];
    __shared__ float s_dn[NPTS];
    __shared__ int   s_lab[NPTS] __attribute__((aligned(16)));
    __shared__ int   s_cp[NW2], s_cn[NW2];
    __shared__ float s_red[NW2];
    __shared__ int   s_nv[NW2];

    const int t = threadIdx.x, lane = t & 63, w = t >> 6;
    const int b = blockIdx.x;

    s_lab[t] = labels[t];
    __syncthreads();

    const unsigned long long blw = (1ull << lane) - 1ull;   // lane<64, safe
    float local = 0.f;
#pragma unroll 1
    for (int g = 0; g < APB; ++g) {
        const int a     = b * APB + g;
        const int lab_a = s_lab[a];
        const float dv  = D[(size_t)a * NPTS + t];
        const bool  isp = (s_lab[t] == lab_a);   // diag j==a counts as pos
        const unsigned long long m = __ballot(isp);
        __syncthreads();                         // prev-g s_dp/s_dn reads done
        if (lane == 0) { s_cp[w] = __popcll(m); s_cn[w] = 64 - __popcll(m); }
        __syncthreads();

        int basep = 0, basen = 0, np = 0, nn = 0;
#pragma unroll
        for (int i = 0; i < NW2; ++i) {
            if (i < w) { basep += s_cp[i]; basen += s_cn[i]; }
            np += s_cp[i]; nn += s_cn[i];
        }
        if (isp) s_dp[basep + __popcll(m  & blw)] = dv;
        else     s_dn[basen + __popcll(~m & blw)] = dv;
        __syncthreads();

        const bool  va  = (t < nn);
        const float dna = va ? s_dn[t] : 0.f;
        for (int p = 0; p < np; ++p) {
            const float c = s_dp[p] + 1.0f;      // MARGIN
            if (va) local += fmaxf(c - dna, 0.f);
        }
    }

    // ---- global num_valid from labels alone (identical in every block) -----
    const int myl = s_lab[t];
    int npt = 0;
    const int4* L4 = (const int4*)s_lab;
#pragma unroll 8
    for (int j4 = 0; j4 < NPTS / 4; ++j4) {
        const int4 l = L4[j4];                   // broadcast read
        npt += (l.x == myl) + (l.y == myl) + (l.z == myl) + (l.w == myl);
    }
    int nvl = npt * (NPTS - npt);

    // ---- block reduce + atomic finish --------------------------------------
    for (int off = 32; off; off >>= 1) {
        local += __shfl_down(local, off, 64);
        nvl   += __shfl_down(nvl,   off, 64);
    }
    if (lane == 0) { s_red[w] = local; s_nv[w] = nvl; }
    __syncthreads();
    if (t == 0) {
        float bs = 0.f; int nv = 0;
#pragma unroll
        for (int i = 0; i < NW2; ++i) { bs += s_red[i]; nv += s_nv[i]; }
        // out is memset to 0 by the harness before each verified launch
        atomicAdd(out, (float)((double)bs / ((double)nv + 1e-16)));
    }
}

extern "C" void kernel_launch(void* const* d_in, const int* in_sizes, int n_in,
                              void* d_out, int out_size, void* d_ws, size_t ws_size,
                              hipStream_t stream) {
    (void)in_sizes; (void)n_in; (void)out_size; (void)ws_size;
    const float* X      = (const float*)d_in[0];
    const int*   labels = (const int*)d_in[1];

    float* Dmat = (float*)d_ws;                  // 589824 B, rewritten each run

    dist_mfma  <<<dim3(NPTS / 32, NPTS / 32), dim3(256), 0, stream>>>(X, Dmat);
    pair_reduce<<<dim3(NB2),                  dim3(NT2), 0, stream>>>(Dmat, labels,
                                                                     (float*)d_out);
}